// Round 2
// baseline (599.531 us; speedup 1.0000x reference)
//
#include <hip/hip_runtime.h>
#include <hip/hip_bf16.h>
#include <stdint.h>

typedef __attribute__((ext_vector_type(8))) short short8;
typedef __attribute__((ext_vector_type(4))) short short4v;
typedef __attribute__((ext_vector_type(4))) float floatx4;
typedef __attribute__((ext_vector_type(4))) int int4v;

#define MFMA16(a, b, c) __builtin_amdgcn_mfma_f32_16x16x32_bf16(a, b, c, 0, 0, 0)

static constexpr int kHW = 4096;   // 64*64 spatial positions per batch
static constexpr int kC  = 256;
static constexpr int kD  = 32;     // C/8 (qk dim)
static constexpr int kDV = 128;    // C/2 (v dim)

__device__ __forceinline__ short f2bf(float f) {
  union { float f; uint32_t u; } v; v.f = f;
  uint32_t r = (v.u + 0x7FFFu + ((v.u >> 16) & 1u)) >> 16;  // RNE
  return (short)(uint16_t)r;
}
__device__ __forceinline__ float bf2f(short s) {
  union { uint32_t u; float f; } v; v.u = ((uint32_t)(uint16_t)s) << 16;
  return v.f;
}
// split float into hi+lo bf16 (hi = RNE(f), lo = RNE(f - hi))
__device__ __forceinline__ void split_bf(float f, short& hi, short& lo) {
  hi = f2bf(f);
  lo = f2bf(f - bf2f(hi));
}

// ---------------------------------------------------------------------------
// Kernel 1: f = xWf+bf, g = xWg+bg, h = xWh+bh, computed in split-bf16
// precision (xh*wh + xh*wl + xl*wh ~= fp32).  f,g stored as hi/lo bf16 pairs;
// h stored TRANSPOSED single bf16 [b][128][4096].
// Block: 64 pixels, 256 threads (4 waves x 16 rows). K=256 in 8 panels of 32.
// ---------------------------------------------------------------------------
__global__ __launch_bounds__(256) void fgh_kernel(
    const float* __restrict__ x,
    const float* __restrict__ Wf, const float* __restrict__ bf,
    const float* __restrict__ Wg, const float* __restrict__ bg,
    const float* __restrict__ Wh, const float* __restrict__ bh,
    short* __restrict__ f_h, short* __restrict__ f_l,
    short* __restrict__ g_h, short* __restrict__ g_l,
    short* __restrict__ hT) {
  __shared__ __align__(16) char smem[2 * 192 * 40 * 2];  // 30.7 KB
  short (*Wp_h)[40] = reinterpret_cast<short (*)[40]>(smem);
  short (*Wp_l)[40] = reinterpret_cast<short (*)[40]>(smem + 192 * 40 * 2);

  const int tid  = threadIdx.x;
  const int lane = tid & 63;
  const int w    = tid >> 6;      // wave 0..3
  const int cl   = lane & 15;
  const int row4 = lane >> 4;     // 0..3
  const int px0  = blockIdx.x * 64;

  // per-lane A fragments for all 8 K-panels, split hi/lo
  short8 xh[8], xl[8];
  const float* xr = x + (size_t)(px0 + w * 16 + cl) * kC + row4 * 8;
#pragma unroll
  for (int kp = 0; kp < 8; ++kp) {
    float4 v0 = *reinterpret_cast<const float4*>(xr + kp * 32);
    float4 v1 = *reinterpret_cast<const float4*>(xr + kp * 32 + 4);
    float vv[8] = {v0.x, v0.y, v0.z, v0.w, v1.x, v1.y, v1.z, v1.w};
#pragma unroll
    for (int e = 0; e < 8; ++e) { short h, l; split_bf(vv[e], h, l); xh[kp][e] = h; xl[kp][e] = l; }
  }

  floatx4 acc[12];
#pragma unroll
  for (int i = 0; i < 12; ++i) acc[i] = (floatx4){0.f, 0.f, 0.f, 0.f};

#pragma unroll
  for (int kp = 0; kp < 8; ++kp) {
    const int k0 = kp * 32;
    __syncthreads();  // prev panel reads done
    for (int i = tid; i < 192 * 32; i += 256) {
      int c = i % 192, k = i / 192;
      float wv;
      if (c < 32)       wv = Wf[(size_t)(k0 + k) * 32 + c];
      else if (c < 64)  wv = Wg[(size_t)(k0 + k) * 32 + (c - 32)];
      else              wv = Wh[(size_t)(k0 + k) * 128 + (c - 64)];
      short h, l; split_bf(wv, h, l);
      Wp_h[c][k] = h; Wp_l[c][k] = l;
    }
    __syncthreads();
#pragma unroll
    for (int ct = 0; ct < 12; ++ct) {
      short8 bh_ = *reinterpret_cast<const short8*>(&Wp_h[ct * 16 + cl][row4 * 8]);
      short8 bl_ = *reinterpret_cast<const short8*>(&Wp_l[ct * 16 + cl][row4 * 8]);
      acc[ct] = MFMA16(xh[kp], bh_, acc[ct]);
      acc[ct] = MFMA16(xh[kp], bl_, acc[ct]);
      acc[ct] = MFMA16(xl[kp], bh_, acc[ct]);
    }
  }

  // f and g: split hi/lo bf16 stores
#pragma unroll
  for (int ct = 0; ct < 4; ++ct) {
    int c = ct * 16 + cl;
    float bias = (c < 32) ? bf[c] : bg[c - 32];
    const int cc = (c < 32) ? c : (c - 32);
    short* dh = (c < 32) ? f_h : g_h;
    short* dl = (c < 32) ? f_l : g_l;
#pragma unroll
    for (int j = 0; j < 4; ++j) {
      int pix = px0 + w * 16 + row4 * 4 + j;
      short h, l; split_bf(acc[ct][j] + bias, h, l);
      dh[(size_t)pix * kD + cc] = h;
      dl[(size_t)pix * kD + cc] = l;
    }
  }

  __syncthreads();  // Wp reads done before smem reuse
  // h: stage tile in LDS (reuse smem), then write transposed coalesced
  short (*ht)[132] = reinterpret_cast<short (*)[132]>(smem);  // 64 x 128 = 16.9KB
#pragma unroll
  for (int ct = 4; ct < 12; ++ct) {
    int cv = ct * 16 - 64 + cl;  // 0..127
    float bias = bh[cv];
#pragma unroll
    for (int j = 0; j < 4; ++j)
      ht[w * 16 + row4 * 4 + j][cv] = f2bf(acc[ct][j] + bias);
  }
  __syncthreads();
  const int b = px0 >> 12;          // batch (64 | 4096 so constant per block)
  const int pb0 = px0 & 4095;
  for (int e = tid; e < 128 * 64; e += 256) {
    int dv = e >> 6, p = e & 63;
    hT[((size_t)b * kDV + dv) * kHW + pb0 + p] = ht[p][dv];
  }
}

// ---------------------------------------------------------------------------
// Kernel 2: flash attention with split-precision QK^T.
// Block = 1 batch x 128 queries, 512 threads (8 waves x 16 q-rows).
// ---------------------------------------------------------------------------
__global__ __launch_bounds__(512) void attn_kernel(
    const short* __restrict__ fkh, const short* __restrict__ fkl,  // keys hi/lo [b][4096][32]
    const short* __restrict__ gqh, const short* __restrict__ gql,  // queries hi/lo
    const short* __restrict__ hT,   // values [b][128][4096] bf16 (transposed)
    short* __restrict__ og) {       // out    [b][4096][128] bf16
  __shared__ short Plds[8][16][72];  // per-wave P tile [16 q][64 k], padded
  __shared__ short Vt[128][72];      // V tile [dv][64 keys], padded

  const int tid  = threadIdx.x;
  const int lane = tid & 63;
  const int w    = tid >> 6;       // 0..7
  const int cl   = lane & 15;
  const int row4 = lane >> 4;
  const int b    = blockIdx.x >> 5;
  const int q0   = (blockIdx.x & 31) * 128;

  // Q fragments hi/lo: rows q0+w*16+cl, k contiguous — in registers all kernel
  const size_t qoff = ((size_t)b * kHW + q0 + w * 16 + cl) * kD + row4 * 8;
  short8 qh = *reinterpret_cast<const short8*>(gqh + qoff);
  short8 ql = *reinterpret_cast<const short8*>(gql + qoff);

  floatx4 acc[8];
#pragma unroll
  for (int i = 0; i < 8; ++i) acc[i] = (floatx4){0.f, 0.f, 0.f, 0.f};
  float m[4], ls[4];
#pragma unroll
  for (int j = 0; j < 4; ++j) { m[j] = -1e30f; ls[j] = 0.f; }

  for (int kb = 0; kb < 64; ++kb) {
    const int k0 = kb * 64;
    __syncthreads();  // protect Vt from previous iteration's readers
    // stage V tile: Vt[dv][0..64) = hT[b][dv][k0..k0+64)
    for (int e = tid; e < 1024; e += 512) {
      int dv = e >> 3, part = e & 7;
      *reinterpret_cast<int4v*>(&Vt[dv][part * 8]) =
          *reinterpret_cast<const int4v*>(hT + ((size_t)b * kDV + dv) * kHW + k0 + part * 8);
    }

    // S = Q K^T for 64 keys (4 col-subtiles), split precision
    floatx4 s_[4];
#pragma unroll
    for (int kt = 0; kt < 4; ++kt) {
      const size_t koff = ((size_t)b * kHW + k0 + kt * 16 + cl) * kD + row4 * 8;
      short8 fbh = *reinterpret_cast<const short8*>(fkh + koff);
      short8 fbl = *reinterpret_cast<const short8*>(fkl + koff);
      floatx4 t = MFMA16(qh, fbh, ((floatx4){0.f, 0.f, 0.f, 0.f}));
      t = MFMA16(qh, fbl, t);
      t = MFMA16(ql, fbh, t);
      s_[kt] = t;
    }

    // online softmax (row r = row4*4+j, cols spread over 16 lanes)
    float pm[4];
#pragma unroll
    for (int j = 0; j < 4; ++j)
      pm[j] = fmaxf(fmaxf(s_[0][j], s_[1][j]), fmaxf(s_[2][j], s_[3][j]));
#pragma unroll
    for (int off = 1; off < 16; off <<= 1)
#pragma unroll
      for (int j = 0; j < 4; ++j)
        pm[j] = fmaxf(pm[j], __shfl_xor(pm[j], off, 16));

    float sc_[4];
#pragma unroll
    for (int j = 0; j < 4; ++j) {
      float mn = fmaxf(m[j], pm[j]);
      sc_[j] = __expf(m[j] - mn);
      m[j] = mn;
    }
    float p[4][4];
#pragma unroll
    for (int kt = 0; kt < 4; ++kt)
#pragma unroll
      for (int j = 0; j < 4; ++j)
        p[kt][j] = __expf(s_[kt][j] - m[j]);
    float rs[4];
#pragma unroll
    for (int j = 0; j < 4; ++j) rs[j] = (p[0][j] + p[1][j]) + (p[2][j] + p[3][j]);
#pragma unroll
    for (int off = 1; off < 16; off <<= 1)
#pragma unroll
      for (int j = 0; j < 4; ++j) rs[j] += __shfl_xor(rs[j], off, 16);
#pragma unroll
    for (int j = 0; j < 4; ++j) ls[j] = ls[j] * sc_[j] + rs[j];
#pragma unroll
    for (int ct = 0; ct < 8; ++ct)
#pragma unroll
      for (int j = 0; j < 4; ++j) acc[ct][j] *= sc_[j];

    // P -> LDS (transpose to A-operand layout), per-wave region
#pragma unroll
    for (int kt = 0; kt < 4; ++kt)
#pragma unroll
      for (int j = 0; j < 4; ++j)
        Plds[w][row4 * 4 + j][kt * 16 + cl] = f2bf(p[kt][j]);

    __syncthreads();  // Vt staged + P visible

    // O += P V
#pragma unroll
    for (int ks = 0; ks < 2; ++ks) {
      short8 pa = *reinterpret_cast<const short8*>(&Plds[w][cl][ks * 32 + row4 * 8]);
#pragma unroll
      for (int ct = 0; ct < 8; ++ct) {
        short8 vb = *reinterpret_cast<const short8*>(&Vt[ct * 16 + cl][ks * 32 + row4 * 8]);
        acc[ct] = MFMA16(pa, vb, acc[ct]);
      }
    }
  }

  float inv[4];
#pragma unroll
  for (int j = 0; j < 4; ++j) inv[j] = 1.0f / ls[j];
#pragma unroll
  for (int ct = 0; ct < 8; ++ct)
#pragma unroll
    for (int j = 0; j < 4; ++j) {
      int qr = q0 + w * 16 + row4 * 4 + j;
      og[((size_t)b * kHW + qr) * kDV + ct * 16 + cl] = f2bf(acc[ct][j] * inv[j]);
    }
}

// ---------------------------------------------------------------------------
// Kernel 3: out = x + o @ Wo + bo.  Wo split hi/lo for precision.
// Block = 64 pixels, 256 threads (4 waves).
// ---------------------------------------------------------------------------
__global__ __launch_bounds__(256) void outproj_kernel(
    const short* __restrict__ o,   // [pix][128] bf16
    const float* __restrict__ Wo,  // [128][256]
    const float* __restrict__ bo,  // [256]
    const float* __restrict__ x,   // [pix][256]
    float* __restrict__ out) {     // [pix][256]
  __shared__ short Wp_h[256][40];  // K-panel transposed [col][k], padded
  __shared__ short Wp_l[256][40];

  const int tid  = threadIdx.x;
  const int lane = tid & 63;
  const int w    = tid >> 6;
  const int cl   = lane & 15;
  const int row4 = lane >> 4;
  const int px0  = blockIdx.x * 64;

  floatx4 acc[16];
#pragma unroll
  for (int i = 0; i < 16; ++i) acc[i] = (floatx4){0.f, 0.f, 0.f, 0.f};

  for (int kp = 0; kp < 4; ++kp) {
    const int k0 = kp * 32;
    __syncthreads();
    for (int i = tid; i < 256 * 32; i += 256) {
      int c = i & 255, k = i >> 8;
      short h, l; split_bf(Wo[(size_t)(k0 + k) * 256 + c], h, l);
      Wp_h[c][k] = h; Wp_l[c][k] = l;
    }
    __syncthreads();
    short8 a = *reinterpret_cast<const short8*>(
        o + (size_t)(px0 + w * 16 + cl) * kDV + k0 + row4 * 8);
#pragma unroll
    for (int ct = 0; ct < 16; ++ct) {
      short8 bh_ = *reinterpret_cast<const short8*>(&Wp_h[ct * 16 + cl][row4 * 8]);
      short8 bl_ = *reinterpret_cast<const short8*>(&Wp_l[ct * 16 + cl][row4 * 8]);
      acc[ct] = MFMA16(a, bh_, acc[ct]);
      acc[ct] = MFMA16(a, bl_, acc[ct]);
    }
  }

#pragma unroll
  for (int ct = 0; ct < 16; ++ct) {
    int c = ct * 16 + cl;
    float bias = bo[c];
#pragma unroll
    for (int j = 0; j < 4; ++j) {
      size_t idx = (size_t)(px0 + w * 16 + row4 * 4 + j) * kC + c;
      out[idx] = x[idx] + acc[ct][j] + bias;
    }
  }
}

// ---------------------------------------------------------------------------
extern "C" void kernel_launch(void* const* d_in, const int* in_sizes, int n_in,
                              void* d_out, int out_size, void* d_ws, size_t ws_size,
                              hipStream_t stream) {
  const float* x  = (const float*)d_in[0];
  const float* Wf = (const float*)d_in[1];
  const float* bf = (const float*)d_in[2];
  const float* Wg = (const float*)d_in[3];
  const float* bg = (const float*)d_in[4];
  const float* Wh = (const float*)d_in[5];
  const float* bh = (const float*)d_in[6];
  const float* Wo = (const float*)d_in[7];
  const float* bo = (const float*)d_in[8];
  float* out = (float*)d_out;

  char* ws = (char*)d_ws;
  const size_t MB = 1024 * 1024;
  short* f_h = (short*)(ws);            //  4 MB: [16*4096][32] bf16
  short* f_l = (short*)(ws + 4  * MB);  //  4 MB
  short* g_h = (short*)(ws + 8  * MB);  //  4 MB
  short* g_l = (short*)(ws + 12 * MB);  //  4 MB
  short* hT  = (short*)(ws + 16 * MB);  // 16 MB: [16][128][4096] bf16
  short* o   = (short*)(ws + 32 * MB);  // 16 MB: [16*4096][128] bf16

  fgh_kernel<<<1024, 256, 0, stream>>>(x, Wf, bf, Wg, bg, Wh, bh,
                                       f_h, f_l, g_h, g_l, hT);
  attn_kernel<<<512, 512, 0, stream>>>(f_h, f_l, g_h, g_l, hT, o);
  outproj_kernel<<<1024, 256, 0, stream>>>(o, Wo, bo, x, out);
}

// Round 3
// 424.093 us; speedup vs baseline: 1.4137x; 1.4137x over previous
//
#include <hip/hip_runtime.h>
#include <hip/hip_bf16.h>
#include <stdint.h>

typedef __attribute__((ext_vector_type(8))) short short8;
typedef __attribute__((ext_vector_type(4))) float floatx4;
typedef __attribute__((ext_vector_type(16))) float floatx16;
typedef __attribute__((ext_vector_type(4))) int int4v;
typedef __attribute__((ext_vector_type(4))) unsigned int uint4v;

#define MFMA16(a, b, c) __builtin_amdgcn_mfma_f32_16x16x32_bf16(a, b, c, 0, 0, 0)
#define MFMA32(a, b, c) __builtin_amdgcn_mfma_f32_32x32x16_bf16(a, b, c, 0, 0, 0)

static constexpr int kHW = 4096;
static constexpr int kC  = 256;
static constexpr int kD  = 32;
static constexpr int kDV = 128;

__device__ __forceinline__ short f2bf(float f) {
  union { float f; uint32_t u; } v; v.f = f;
  uint32_t r = (v.u + 0x7FFFu + ((v.u >> 16) & 1u)) >> 16;  // RNE
  return (short)(uint16_t)r;
}
__device__ __forceinline__ float bf2f(short s) {
  union { uint32_t u; float f; } v; v.u = ((uint32_t)(uint16_t)s) << 16;
  return v.f;
}
__device__ __forceinline__ void split_bf(float f, short& hi, short& lo) {
  hi = f2bf(f);
  lo = f2bf(f - bf2f(hi));
}
__device__ __forceinline__ uint32_t pk2(float a, float b) {  // bf16x2: a in low half
  return (uint32_t)(uint16_t)f2bf(a) | ((uint32_t)(uint16_t)f2bf(b) << 16);
}
__device__ __forceinline__ short8 mkfrag(uint32_t a, uint32_t b, uint32_t c, uint32_t d) {
  uint4v t = {a, b, c, d};
  return __builtin_bit_cast(short8, t);
}

// ---------------------------------------------------------------------------
// Kernel 0: one-time weight prep.  Split fp32 -> (hi,lo) bf16, transposed:
//   Wt  [192 cols][256 k]  = [Wf | Wg | Wh]^T      (hi and lo planes)
//   Wot [256 cols][128 k]  = Wo^T                  (hi and lo planes)
// ---------------------------------------------------------------------------
__global__ __launch_bounds__(256) void prep_kernel(
    const float* __restrict__ Wf, const float* __restrict__ Wg,
    const float* __restrict__ Wh, const float* __restrict__ Wo,
    short* __restrict__ Wt_h, short* __restrict__ Wt_l,
    short* __restrict__ Wot_h, short* __restrict__ Wot_l) {
  const int i = blockIdx.x * 256 + threadIdx.x;
  const int total1 = 192 * 256;
  if (i < total1) {
    int c = i >> 8, k = i & 255;
    float wv;
    if (c < 32)       wv = Wf[(size_t)k * 32 + c];
    else if (c < 64)  wv = Wg[(size_t)k * 32 + (c - 32)];
    else              wv = Wh[(size_t)k * 128 + (c - 64)];
    short h, l; split_bf(wv, h, l);
    Wt_h[i] = h; Wt_l[i] = l;
  } else {
    int j = i - total1;             // j < 256*128
    int c = j >> 7, k = j & 127;
    short h, l; split_bf(Wo[(size_t)k * 256 + c], h, l);
    Wot_h[j] = h; Wot_l[j] = l;
  }
}

// ---------------------------------------------------------------------------
// Kernel 1: f,g,h projections, split-bf16 precision.  B-fragments loaded
// directly from pre-split transposed weights in global (L2-resident).
// Block = 128 px, 256 thr (4 waves x 2 M-tiles of 16 rows).
// ---------------------------------------------------------------------------
__global__ __launch_bounds__(256, 3) void fgh_kernel(
    const float* __restrict__ x,
    const float* __restrict__ bfv, const float* __restrict__ bgv,
    const float* __restrict__ bhv,
    const short* __restrict__ Wt_h, const short* __restrict__ Wt_l,
    short* __restrict__ f_h, short* __restrict__ f_l,
    short* __restrict__ g_h, short* __restrict__ g_l,
    short* __restrict__ hT) {
  __shared__ short ht2[128][136];   // [dv][px] for coalesced hT write, 34.8 KB

  const int tid  = threadIdx.x;
  const int lane = tid & 63;
  const int w    = tid >> 6;
  const int cl   = lane & 15;
  const int row4 = lane >> 4;
  const int px0  = blockIdx.x * 128;

  floatx4 acc[2][12];
#pragma unroll
  for (int mt = 0; mt < 2; ++mt)
#pragma unroll
    for (int i = 0; i < 12; ++i) acc[mt][i] = (floatx4){0.f, 0.f, 0.f, 0.f};

#pragma unroll
  for (int kp = 0; kp < 8; ++kp) {
    short8 xh[2], xl[2];
#pragma unroll
    for (int mt = 0; mt < 2; ++mt) {
      const float* xr = x + (size_t)(px0 + w * 32 + mt * 16 + cl) * kC + kp * 32 + row4 * 8;
      float4 v0 = *reinterpret_cast<const float4*>(xr);
      float4 v1 = *reinterpret_cast<const float4*>(xr + 4);
      float vv[8] = {v0.x, v0.y, v0.z, v0.w, v1.x, v1.y, v1.z, v1.w};
#pragma unroll
      for (int e = 0; e < 8; ++e) {
        short h, l; split_bf(vv[e], h, l);
        xh[mt][e] = h; xl[mt][e] = l;
      }
    }
#pragma unroll
    for (int ct = 0; ct < 12; ++ct) {
      const size_t woff = (size_t)(ct * 16 + cl) * 256 + kp * 32 + row4 * 8;
      short8 bh_ = *reinterpret_cast<const short8*>(Wt_h + woff);
      short8 bl_ = *reinterpret_cast<const short8*>(Wt_l + woff);
#pragma unroll
      for (int mt = 0; mt < 2; ++mt) {
        acc[mt][ct] = MFMA16(xh[mt], bh_, acc[mt][ct]);
        acc[mt][ct] = MFMA16(xh[mt], bl_, acc[mt][ct]);
        acc[mt][ct] = MFMA16(xl[mt], bh_, acc[mt][ct]);
      }
    }
  }

  // f and g: split hi/lo stores
#pragma unroll
  for (int mt = 0; mt < 2; ++mt)
#pragma unroll
    for (int ct = 0; ct < 4; ++ct) {
      int c = ct * 16 + cl;
      float bias = (c < 32) ? bfv[c] : bgv[c - 32];
      const int cc = (c < 32) ? c : (c - 32);
      short* dh = (c < 32) ? f_h : g_h;
      short* dl = (c < 32) ? f_l : g_l;
#pragma unroll
      for (int j = 0; j < 4; ++j) {
        int pix = px0 + w * 32 + mt * 16 + row4 * 4 + j;
        short h, l; split_bf(acc[mt][ct][j] + bias, h, l);
        dh[(size_t)pix * kD + cc] = h;
        dl[(size_t)pix * kD + cc] = l;
      }
    }

  // h: transpose via LDS, write hT[b][dv][pix] coalesced
#pragma unroll
  for (int mt = 0; mt < 2; ++mt)
#pragma unroll
    for (int ct = 4; ct < 12; ++ct) {
      int dv = (ct - 4) * 16 + cl;
      float bias = bhv[dv];
#pragma unroll
      for (int j = 0; j < 4; ++j)
        ht2[dv][w * 32 + mt * 16 + row4 * 4 + j] = f2bf(acc[mt][ct][j] + bias);
    }
  __syncthreads();
  const int b   = px0 >> 12;
  const int pb0 = px0 & 4095;
#pragma unroll
  for (int it = 0; it < 8; ++it) {
    int c = tid + it * 256;          // 0..2047
    int dv = c >> 4, p8 = c & 15;
    int4v v = *reinterpret_cast<const int4v*>(&ht2[dv][p8 * 8]);
    *reinterpret_cast<int4v*>(hT + ((size_t)(b * kDV + dv)) * kHW + pb0 + p8 * 8) = v;
  }
}

// ---------------------------------------------------------------------------
// Kernel 2: flash attention, swapped-operand 32x32 MFMA.
// Block = 1 batch x 128 queries, 256 thr (4 waves x 32 queries each).
// S^T = mfma(K,Q): lane owns query cl=lane&31; keys split hi=lane>>5.
// PV: A = V^T rows from XOR-swizzled LDS; B = P^T built in-register.
// ---------------------------------------------------------------------------
__global__ __launch_bounds__(256, 3) void attn_kernel(
    const short* __restrict__ fkh, const short* __restrict__ fkl,
    const short* __restrict__ gqh, const short* __restrict__ gql,
    const short* __restrict__ hT,
    short* __restrict__ og) {
  __shared__ __align__(16) char smem[34816];  // Vt[128][128] swz (32KB) / ot 4x[32][136]
  char* Vb = smem;

  const int tid  = threadIdx.x;
  const int lane = tid & 63;
  const int w    = tid >> 6;       // 0..3
  const int cl   = lane & 31;
  const int hi   = lane >> 5;      // 0..1
  const int bb   = blockIdx.x >> 5;
  const int q0   = (blockIdx.x & 31) * 128;
  const int qw   = q0 + w * 32;

  const size_t qbase = ((size_t)bb * kHW + qw + cl) * kD + hi * 8;
  const short8 qh0 = *reinterpret_cast<const short8*>(gqh + qbase);
  const short8 qh1 = *reinterpret_cast<const short8*>(gqh + qbase + 16);
  const short8 ql0 = *reinterpret_cast<const short8*>(gql + qbase);
  const short8 ql1 = *reinterpret_cast<const short8*>(gql + qbase + 16);

  const floatx16 z16 = {0.f,0.f,0.f,0.f,0.f,0.f,0.f,0.f,0.f,0.f,0.f,0.f,0.f,0.f,0.f,0.f};
  floatx16 acc[4];
#pragma unroll
  for (int i = 0; i < 4; ++i) acc[i] = z16;
  float m = -1e30f, ls = 0.f;

  for (int kb0 = 0; kb0 < 32; ++kb0) {
    __syncthreads();   // prior Vt readers done
    // stage V^T tile (swizzled): Vt[dv][key], 128 dv x 128 keys
#pragma unroll
    for (int it = 0; it < 8; ++it) {
      int c = tid + it * 256;        // 0..2047 16B-chunks
      int dv = c >> 4, k16 = c & 15;
      uint4v v = *reinterpret_cast<const uint4v*>(
          hT + ((size_t)(bb * kDV + dv)) * kHW + kb0 * 128 + k16 * 8);
      *reinterpret_cast<uint4v*>(Vb + dv * 256 + ((k16 * 16) ^ ((dv & 15) << 4))) = v;
    }
    __syncthreads();

#pragma unroll
    for (int t = 0; t < 4; ++t) {    // 4 x 32-key S-tiles
      const int kk = kb0 * 128 + t * 32;
      const size_t kbse = ((size_t)bb * kHW + kk + cl) * kD + hi * 8;
      short8 kh0 = *reinterpret_cast<const short8*>(fkh + kbse);
      short8 kh1 = *reinterpret_cast<const short8*>(fkh + kbse + 16);
      short8 kl0 = *reinterpret_cast<const short8*>(fkl + kbse);
      short8 kl1 = *reinterpret_cast<const short8*>(fkl + kbse + 16);

      floatx16 sA = MFMA32(kh0, qh0, z16);
      sA = MFMA32(kh1, qh1, sA);
      sA = MFMA32(kl0, qh0, sA);
      floatx16 sB = MFMA32(kl1, qh1, z16);
      sB = MFMA32(kh0, ql0, sB);
      sB = MFMA32(kh1, ql1, sB);

      float pr[16];
      float tm = -1e30f;
#pragma unroll
      for (int r = 0; r < 16; ++r) {
        float sv = sA[r] + sB[r];
        pr[r] = sv;
        tm = fmaxf(tm, sv);
      }
      tm = fmaxf(tm, __shfl_xor(tm, 32));

      if (__any(tm > m + 8.0f)) {    // T13 defer-max: rescale only when needed
        float mn = fmaxf(m, tm);
        float sc = __expf(m - mn);
        ls *= sc;
#pragma unroll
        for (int ct = 0; ct < 4; ++ct)
#pragma unroll
          for (int r = 0; r < 16; ++r) acc[ct][r] *= sc;
        m = mn;
      }

      float sum = 0.f;
#pragma unroll
      for (int r = 0; r < 16; ++r) {
        pr[r] = __expf(pr[r] - m);
        sum += pr[r];
      }
      ls += sum;

      // pack P^T and exchange halves to form PV B-fragments
      uint32_t pk[8], X[8];
#pragma unroll
      for (int i = 0; i < 8; ++i) pk[i] = pk2(pr[2 * i], pr[2 * i + 1]);
#pragma unroll
      for (int i = 0; i < 8; ++i) X[i] = (uint32_t)__shfl_xor((int)pk[i], 32);
      short8 pf0 = mkfrag(hi ? X[2] : pk[0], hi ? X[3] : pk[1],
                          hi ? pk[2] : X[0], hi ? pk[3] : X[1]);
      short8 pf1 = mkfrag(hi ? X[6] : pk[4], hi ? X[7] : pk[5],
                          hi ? pk[6] : X[4], hi ? pk[7] : X[5]);

      // O^T += V^T P^T
      __builtin_amdgcn_s_setprio(1);
#pragma unroll
      for (int ct = 0; ct < 4; ++ct) {
        int dv = ct * 32 + cl;
        short8 va = *reinterpret_cast<const short8*>(
            Vb + dv * 256 + (((t * 2 + 0) * 32 + hi * 16) ^ ((dv & 15) << 4)));
        acc[ct] = MFMA32(va, pf0, acc[ct]);
      }
#pragma unroll
      for (int ct = 0; ct < 4; ++ct) {
        int dv = ct * 32 + cl;
        short8 va = *reinterpret_cast<const short8*>(
            Vb + dv * 256 + (((t * 2 + 1) * 32 + hi * 16) ^ ((dv & 15) << 4)));
        acc[ct] = MFMA32(va, pf1, acc[ct]);
      }
      __builtin_amdgcn_s_setprio(0);
    }
  }

  ls += __shfl_xor(ls, 32);
  const float inv = 1.0f / ls;

  // epilogue: O^T -> [q][dv] via LDS, coalesced global store
  __syncthreads();                    // Vt no longer needed
  short* ot = reinterpret_cast<short*>(smem) + w * 32 * 136;
#pragma unroll
  for (int ct = 0; ct < 4; ++ct)
#pragma unroll
    for (int r = 0; r < 16; ++r) {
      int dv = ct * 32 + (r & 3) + 8 * (r >> 2) + 4 * hi;
      ot[cl * 136 + dv] = f2bf(acc[ct][r] * inv);
    }
  __syncthreads();
#pragma unroll
  for (int it = 0; it < 8; ++it) {
    int q2 = it * 4 + (lane >> 4);    // 0..31
    int ck = lane & 15;               // 16B chunk of 128 dv
    int4v v = *reinterpret_cast<const int4v*>(ot + q2 * 136 + ck * 8);
    *reinterpret_cast<int4v*>(og + ((size_t)bb * kHW + qw + q2) * kDV + ck * 8) = v;
  }
}

// ---------------------------------------------------------------------------
// Kernel 3: out = x + o @ Wo + bo.  Pre-split Wo^T fragments direct from L2.
// Block = 64 px, 256 thr (4 waves x 16 rows).
// ---------------------------------------------------------------------------
__global__ __launch_bounds__(256, 4) void outproj_kernel(
    const short* __restrict__ o,
    const short* __restrict__ Wot_h, const short* __restrict__ Wot_l,
    const float* __restrict__ bo,
    const float* __restrict__ x,
    float* __restrict__ out) {
  const int tid  = threadIdx.x;
  const int lane = tid & 63;
  const int w    = tid >> 6;
  const int cl   = lane & 15;
  const int row4 = lane >> 4;
  const int px0  = blockIdx.x * 64;

  floatx4 acc[16];
#pragma unroll
  for (int i = 0; i < 16; ++i) acc[i] = (floatx4){0.f, 0.f, 0.f, 0.f};

#pragma unroll
  for (int kp = 0; kp < 4; ++kp) {
    short8 a = *reinterpret_cast<const short8*>(
        o + (size_t)(px0 + w * 16 + cl) * kDV + kp * 32 + row4 * 8);
#pragma unroll
    for (int ct = 0; ct < 16; ++ct) {
      const size_t woff = (size_t)(ct * 16 + cl) * 128 + kp * 32 + row4 * 8;
      short8 bh_ = *reinterpret_cast<const short8*>(Wot_h + woff);
      short8 bl_ = *reinterpret_cast<const short8*>(Wot_l + woff);
      acc[ct] = MFMA16(a, bh_, acc[ct]);
      acc[ct] = MFMA16(a, bl_, acc[ct]);
    }
  }

#pragma unroll
  for (int ct = 0; ct < 16; ++ct) {
    int c = ct * 16 + cl;
    float bias = bo[c];
#pragma unroll
    for (int j = 0; j < 4; ++j) {
      size_t idx = (size_t)(px0 + w * 16 + row4 * 4 + j) * kC + c;
      out[idx] = x[idx] + acc[ct][j] + bias;
    }
  }
}

// ---------------------------------------------------------------------------
extern "C" void kernel_launch(void* const* d_in, const int* in_sizes, int n_in,
                              void* d_out, int out_size, void* d_ws, size_t ws_size,
                              hipStream_t stream) {
  const float* x  = (const float*)d_in[0];
  const float* Wf = (const float*)d_in[1];
  const float* bf = (const float*)d_in[2];
  const float* Wg = (const float*)d_in[3];
  const float* bg = (const float*)d_in[4];
  const float* Wh = (const float*)d_in[5];
  const float* bh = (const float*)d_in[6];
  const float* Wo = (const float*)d_in[7];
  const float* bo = (const float*)d_in[8];
  float* out = (float*)d_out;

  char* ws = (char*)d_ws;
  const size_t MB = 1024 * 1024;
  short* f_h = (short*)(ws);             //  4 MB  [65536][32] bf16
  short* f_l = (short*)(ws + 4  * MB);   //  4 MB
  short* g_h = (short*)(ws + 8  * MB);   //  4 MB
  short* g_l = (short*)(ws + 12 * MB);   //  4 MB
  short* hT  = (short*)(ws + 16 * MB);   // 16 MB  [16][128][4096] bf16
  short* o   = (short*)(ws + 32 * MB);   // 16 MB  [65536][128] bf16
  short* Wt_h  = (short*)(ws + 48 * MB);            //  96 KB [192][256]
  short* Wt_l  = (short*)(ws + 48 * MB + 98304);    //  96 KB
  short* Wot_h = (short*)(ws + 48 * MB + 196608);   //  64 KB [256][128]
  short* Wot_l = (short*)(ws + 48 * MB + 262144);   //  64 KB

  prep_kernel<<<320, 256, 0, stream>>>(Wf, Wg, Wh, Wo, Wt_h, Wt_l, Wot_h, Wot_l);
  fgh_kernel<<<512, 256, 0, stream>>>(x, bf, bg, bh, Wt_h, Wt_l,
                                      f_h, f_l, g_h, g_l, hT);
  attn_kernel<<<512, 256, 0, stream>>>(f_h, f_l, g_h, g_l, hT, o);
  outproj_kernel<<<1024, 256, 0, stream>>>(o, Wot_h, Wot_l, bo, x, out);
}